// Round 8
// baseline (221.452 us; speedup 1.0000x reference)
//
#include <hip/hip_runtime.h>
#include <stdint.h>

#define BB 2
#define NN 4096
#define KNB 20
#define DD 128
#define PHH 8
#define AHH 512
#define BN (BB*NN)

typedef unsigned short ushort_t;
typedef short bf16x8 __attribute__((ext_vector_type(8)));
typedef float f32x4 __attribute__((ext_vector_type(4)));

__device__ __forceinline__ uint32_t umin32(uint32_t a, uint32_t b) { return a < b ? a : b; }
__device__ __forceinline__ uint32_t umax32(uint32_t a, uint32_t b) { return a > b ? a : b; }

__device__ __forceinline__ ushort_t f2bf(float f) {   // RNE
    uint32_t x = __float_as_uint(f);
    return (ushort_t)((x + 0x7FFFu + ((x >> 16) & 1u)) >> 16);
}
__device__ __forceinline__ float bf2f(ushort_t u) {
    union { float f; uint32_t i; } c; c.i = ((uint32_t)u) << 16; return c.f;
}
__device__ __forceinline__ uint32_t cvt_pk_bf16(float lo, float hi) {
    uint32_t r;
    asm("v_cvt_pk_bf16_f32 %0, %1, %2" : "=v"(r) : "v"(lo), "v"(hi));
    return r;  // lo16 = bf16(lo), hi16 = bf16(hi)
}
__device__ __forceinline__ bf16x8 load_bfrag(const float* __restrict__ src) {
    float4 x = *(const float4*)src;
    float4 y = *(const float4*)(src + 4);
    union { bf16x8 v; uint32_t u[4]; } r;
    r.u[0] = cvt_pk_bf16(x.x, x.y);
    r.u[1] = cvt_pk_bf16(x.z, x.w);
    r.u[2] = cvt_pk_bf16(y.x, y.y);
    r.u[3] = cvt_pk_bf16(y.z, y.w);
    return r.v;
}

#define SW256(m, byteInRow) ((m)*256 + ((byteInRow) ^ (((m)&7) << 4)))

// ================= mega: knn(2048) || front(256) || prep(72) =================
__global__ __launch_bounds__(256) void k_mega(
        const float* __restrict__ x, const float* __restrict__ pos,
        const float* __restrict__ W1, const float* __restrict__ b1,
        const float* __restrict__ W2f, const float* __restrict__ b2,
        const float* __restrict__ Wqkvf,
        const float* __restrict__ Wa1, const float* __restrict__ Wa2,
        const float* __restrict__ W3,
        float* __restrict__ h, ushort_t* __restrict__ qf,
        ushort_t* __restrict__ kf, ushort_t* __restrict__ vf,
        int* __restrict__ idx, ushort_t* __restrict__ wbf) {
    __shared__ __align__(16) char smem[16896];
    int tid = threadIdx.x, w = tid >> 6, lane = tid & 63;
    int bid = blockIdx.x;

    if (bid < BN/4) {
        // ---------------- KNN: one wave per query ----------------
        int p = bid*4 + w;
        int b = p >> 12;
        float qx = pos[p*3+0], qy = pos[p*3+1], qz = pos[p*3+2];
        const float* pb = pos + (size_t)b*NN*3;
        uint32_t bk[KNB];
        #pragma unroll
        for (int i = 0; i < KNB; ++i) bk[i] = 0xFFFFFFFFu;
        for (int i = 0; i < NN/64; ++i) {
            int j = i*64 + lane;
            float dx = qx - pb[j*3+0];
            float dy = qy - pb[j*3+1];
            float dz = qz - pb[j*3+2];
            float d2 = dx*dx + dy*dy + dz*dz;
            uint32_t key = (__float_as_uint(d2) & 0xFFFFF000u) | (uint32_t)j;
            if (key < bk[KNB-1]) {
                uint32_t c = key;
                #pragma unroll
                for (int t = 0; t < KNB; ++t) {
                    uint32_t lo = umin32(c, bk[t]);
                    uint32_t hi = umax32(c, bk[t]);
                    bk[t] = lo; c = hi;
                }
            }
        }
        for (int r = 0; r < KNB; ++r) {
            uint32_t m = bk[0];
            #pragma unroll
            for (int s = 1; s < 64; s <<= 1)
                m = umin32(m, (uint32_t)__shfl_xor((int)m, s, 64));
            if (lane == 0) idx[(size_t)p*KNB + r] = (int)(m & 0xFFFu);
            bool win = (bk[0] == m);
            #pragma unroll
            for (int t = 0; t < KNB-1; ++t) bk[t] = win ? bk[t+1] : bk[t];
            bk[KNB-1] = win ? 0xFFFFFFFFu : bk[KNB-1];
        }
    } else if (bid < BN/4 + BN/32) {
        // ---------------- front: lin1 + lin2 + qkv (MFMA) ----------------
        float* xs = (float*)(smem + 16384);
        int p0 = (bid - BN/4) * 32;
        if (tid < 96) xs[tid] = x[(size_t)p0*3 + tid];
        __syncthreads();

        #pragma unroll
        for (int it = 0; it < 16; ++it) {
            int lin = it*256 + tid;
            int m = lin >> 7, d = lin & 127;
            float hv = b1[d] + xs[m*3+0]*W1[d*3+0] + xs[m*3+1]*W1[d*3+1] + xs[m*3+2]*W1[d*3+2];
            h[(size_t)(p0+m)*DD + d] = hv;
            *(ushort_t*)&smem[SW256(m, d*2)] = f2bf(hv);
        }
        __syncthreads();

        {   // h1 = h@W2^T + b2 -> LDS @8192
            f32x4 acc[2][2];
            #pragma unroll
            for (int mt = 0; mt < 2; ++mt)
                #pragma unroll
                for (int ntl = 0; ntl < 2; ++ntl) acc[mt][ntl] = (f32x4){0,0,0,0};
            #pragma unroll
            for (int ks = 0; ks < 4; ++ks) {
                int k0 = ks*32 + (lane >> 4)*8;
                bf16x8 aF[2];
                #pragma unroll
                for (int mt = 0; mt < 2; ++mt)
                    aF[mt] = *(const bf16x8*)&smem[SW256(mt*16 + (lane & 15), k0*2)];
                #pragma unroll
                for (int ntl = 0; ntl < 2; ++ntl) {
                    int n = (2*w + ntl)*16 + (lane & 15);
                    bf16x8 bF = load_bfrag(W2f + (size_t)n*DD + k0);
                    #pragma unroll
                    for (int mt = 0; mt < 2; ++mt)
                        acc[mt][ntl] = __builtin_amdgcn_mfma_f32_16x16x32_bf16(aF[mt], bF, acc[mt][ntl], 0, 0, 0);
                }
            }
            #pragma unroll
            for (int ntl = 0; ntl < 2; ++ntl) {
                int n = (2*w + ntl)*16 + (lane & 15);
                float bias = b2[n];
                #pragma unroll
                for (int mt = 0; mt < 2; ++mt)
                    #pragma unroll
                    for (int i = 0; i < 4; ++i) {
                        int m = mt*16 + (lane >> 4)*4 + i;
                        *(ushort_t*)&smem[8192 + SW256(m, n*2)] = f2bf(acc[mt][ntl][i] + bias);
                    }
            }
        }
        __syncthreads();

        {   // qkv = h1@Wqkv^T, bf16 out
            f32x4 acc[2][6];
            #pragma unroll
            for (int mt = 0; mt < 2; ++mt)
                #pragma unroll
                for (int ntl = 0; ntl < 6; ++ntl) acc[mt][ntl] = (f32x4){0,0,0,0};
            #pragma unroll
            for (int ks = 0; ks < 4; ++ks) {
                int k0 = ks*32 + (lane >> 4)*8;
                bf16x8 aF[2];
                #pragma unroll
                for (int mt = 0; mt < 2; ++mt)
                    aF[mt] = *(const bf16x8*)&smem[8192 + SW256(mt*16 + (lane & 15), k0*2)];
                #pragma unroll
                for (int ntl = 0; ntl < 6; ++ntl) {
                    int n = (w*6 + ntl)*16 + (lane & 15);
                    bf16x8 bF = load_bfrag(Wqkvf + (size_t)n*DD + k0);
                    #pragma unroll
                    for (int mt = 0; mt < 2; ++mt)
                        acc[mt][ntl] = __builtin_amdgcn_mfma_f32_16x16x32_bf16(aF[mt], bF, acc[mt][ntl], 0, 0, 0);
                }
            }
            #pragma unroll
            for (int ntl = 0; ntl < 6; ++ntl) {
                int n = (w*6 + ntl)*16 + (lane & 15);
                int r = n >> 7, d = n & 127;
                ushort_t* dst = (r == 0) ? qf : (r == 1) ? kf : vf;
                #pragma unroll
                for (int mt = 0; mt < 2; ++mt)
                    #pragma unroll
                    for (int i = 0; i < 4; ++i) {
                        int m = mt*16 + (lane >> 4)*4 + i;
                        dst[(size_t)(p0+m)*DD + d] = f2bf(acc[mt][ntl][i]);
                    }
            }
        }
    } else {
        // ---------------- prep: Wa1|Wa2|W3 f32 -> bf16 ----------------
        int base = (bid - (BN/4 + BN/32)) * 2048 + tid * 8;
        const float* src = (base < 65536) ? (Wa1 + base)
                        : (base < 131072) ? (Wa2 + (base - 65536))
                        : (W3 + (base - 131072));
        union { ushort_t u[8]; uint4 q; } pk;
        #pragma unroll
        for (int i = 0; i < 8; ++i) pk.u[i] = f2bf(src[i]);
        *(uint4*)&wbf[base] = pk.q;
    }
}

// ======== attn: pe-MFMA + attn-MLP MFMA (chunk=128) + in-reg softmax + out-epilogue ========
// LDS: XL bf16[80][128]swz @0 (20480) | TL bf16[80][128]swz @20480 (20480)
//      PH bf16[80][8] @40960 (1280) | NIDX @42240 (320). Total 42560 -> 3 blk/CU.
// Epilogue reuses XL region as AGG bf16[16][128]swz.
#define XL_OFF 0
#define TL_OFF 20480
#define PH_OFF 40960
#define NIDX_OFF 42240

__global__ __launch_bounds__(256, 3) void k_attn(
        const float* __restrict__ pos,
        const ushort_t* __restrict__ qf, const ushort_t* __restrict__ kf,
        const ushort_t* __restrict__ vf, const int* __restrict__ idx,
        const float* __restrict__ Wp1, const float* __restrict__ bp1,
        const float* __restrict__ Wp2, const float* __restrict__ bp2,
        const ushort_t* __restrict__ Wa1bf, const float* __restrict__ ba1,
        const ushort_t* __restrict__ Wa2bf, const float* __restrict__ ba2,
        const ushort_t* __restrict__ W3bf, const float* __restrict__ b3,
        const float* __restrict__ h, float* __restrict__ out) {
    __shared__ __align__(16) char smem[42560];
    int* nidx = (int*)(smem + NIDX_OFF);

    int tid = threadIdx.x, w = tid >> 6, lane = tid & 63;
    int lg = lane >> 4, c16 = lane & 15;
    int p0 = blockIdx.x * 4, b = p0 >> 12;

    if (tid < 80) nidx[tid] = idx[(size_t)(p0 + tid/20)*KNB + (tid%20)];
    __syncthreads();

    // A1: pos-MLP hidden, one thread per m-row, packed bf16[8]
    if (tid < 80) {
        int m = tid, g = m / 20;
        int j = nidx[m];
        const float* pq = pos + (size_t)(p0+g)*3;
        const float* pn = pos + (size_t)(b*NN+j)*3;
        float r0 = pq[0]-pn[0], r1 = pq[1]-pn[1], r2 = pq[2]-pn[2];
        union { ushort_t u[8]; uint4 q; } pk;
        #pragma unroll
        for (int jj = 0; jj < PHH; ++jj) {
            float a = bp1[jj] + r0*Wp1[jj*3+0] + r1*Wp1[jj*3+1] + r2*Wp1[jj*3+2];
            pk.u[jj] = f2bf(fmaxf(a, 0.f));
        }
        *(uint4*)&smem[PH_OFF + m*16] = pk.q;
    }
    __syncthreads();

    int dA = w*32 + c16, dB = w*32 + 16 + c16;     // this lane's two d-columns
    float bp2A = bp2[dA], bp2B = bp2[dB];
    float ba2A = ba2[dA], ba2B = ba2[dB];

    // pe-MFMA B-fragments (K padded 8->32: only lg==0 lanes carry data)
    bf16x8 bP0 = {0,0,0,0,0,0,0,0}, bP1 = {0,0,0,0,0,0,0,0};
    if (lg == 0) {
        bP0 = load_bfrag(Wp2 + (size_t)dA*PHH);
        bP1 = load_bfrag(Wp2 + (size_t)dB*PHH);
    }

    float qv[4][2];
    #pragma unroll
    for (int g = 0; g < 4; ++g) {
        qv[g][0] = bf2f(qf[(size_t)(p0+g)*DD + dA]);
        qv[g][1] = bf2f(qf[(size_t)(p0+g)*DD + dB]);
    }

    uint32_t vpe_pk[5][4];   // (v+pe) packed bf16 pairs (dA,dB), [mt][i]

    // A2 fused with pe-MFMA, per m-tile
    #pragma unroll
    for (int mt = 0; mt < 5; ++mt) {
        bf16x8 aP = {0,0,0,0,0,0,0,0};
        if (lg == 0) aP = *(const bf16x8*)&smem[PH_OFF + (mt*16 + c16)*16];
        f32x4 accP0 = (f32x4){0,0,0,0}, accP1 = (f32x4){0,0,0,0};
        accP0 = __builtin_amdgcn_mfma_f32_16x16x32_bf16(aP, bP0, accP0, 0, 0, 0);
        accP1 = __builtin_amdgcn_mfma_f32_16x16x32_bf16(aP, bP1, accP1, 0, 0, 0);
        // q select: g(mt,lg) = [0, lg>=1, 1+(lg>=2), 2+(lg==3), 3]
        float qsA = (mt==0) ? qv[0][0]
                  : (mt==1) ? (lg>=1 ? qv[1][0] : qv[0][0])
                  : (mt==2) ? (lg>=2 ? qv[2][0] : qv[1][0])
                  : (mt==3) ? (lg==3 ? qv[3][0] : qv[2][0])
                  : qv[3][0];
        float qsB = (mt==0) ? qv[0][1]
                  : (mt==1) ? (lg>=1 ? qv[1][1] : qv[0][1])
                  : (mt==2) ? (lg>=2 ? qv[2][1] : qv[1][1])
                  : (mt==3) ? (lg==3 ? qv[3][1] : qv[2][1])
                  : qv[3][1];
        #pragma unroll
        for (int i = 0; i < 4; ++i) {
            int m = mt*16 + lg*4 + i;
            int j = nidx[m];
            const ushort_t* kr = kf + (size_t)(b*NN+j)*DD;
            const ushort_t* vr = vf + (size_t)(b*NN+j)*DD;
            float peA = accP0[i] + bp2A;
            float peB = accP1[i] + bp2B;
            *(ushort_t*)&smem[XL_OFF + SW256(m, dA*2)] = f2bf(qsA - bf2f(kr[dA]) + peA);
            *(ushort_t*)&smem[XL_OFF + SW256(m, dB*2)] = f2bf(qsB - bf2f(kr[dB]) + peB);
            vpe_pk[mt][i] = cvt_pk_bf16(bf2f(vr[dA]) + peA, bf2f(vr[dB]) + peB);
        }
    }
    __syncthreads();

    // attn-MLP: hidden in 4 chunks of 128; SIM accumulates in registers
    f32x4 accS[5][2];
    #pragma unroll
    for (int mt = 0; mt < 5; ++mt)
        #pragma unroll
        for (int ntl = 0; ntl < 2; ++ntl) accS[mt][ntl] = (f32x4){0,0,0,0};

    for (int c = 0; c < 4; ++c) {
        // B: T_chunk = relu(X @ Wa1_c^T + b); wave w owns 32 cols (2 tiles)
        f32x4 accB[5][2];
        #pragma unroll
        for (int mt = 0; mt < 5; ++mt)
            #pragma unroll
            for (int ntl = 0; ntl < 2; ++ntl) accB[mt][ntl] = (f32x4){0,0,0,0};
        __builtin_amdgcn_s_setprio(1);
        #pragma unroll
        for (int ks = 0; ks < 4; ++ks) {
            int k0 = ks*32 + lg*8;
            bf16x8 aF[5];
            #pragma unroll
            for (int mt = 0; mt < 5; ++mt)
                aF[mt] = *(const bf16x8*)&smem[XL_OFF + SW256(mt*16 + c16, k0*2)];
            #pragma unroll
            for (int ntl = 0; ntl < 2; ++ntl) {
                bf16x8 bF = *(const bf16x8*)&Wa1bf[(size_t)(c*128 + w*32 + ntl*16 + c16)*DD + k0];
                #pragma unroll
                for (int mt = 0; mt < 5; ++mt)
                    accB[mt][ntl] = __builtin_amdgcn_mfma_f32_16x16x32_bf16(aF[mt], bF, accB[mt][ntl], 0, 0, 0);
            }
        }
        __builtin_amdgcn_s_setprio(0);
        #pragma unroll
        for (int ntl = 0; ntl < 2; ++ntl) {
            int al = w*32 + ntl*16 + c16;
            float bias = ba1[c*128 + al];
            #pragma unroll
            for (int mt = 0; mt < 5; ++mt)
                #pragma unroll
                for (int i = 0; i < 4; ++i) {
                    int m = mt*16 + lg*4 + i;
                    *(ushort_t*)&smem[TL_OFF + SW256(m, al*2)] = f2bf(fmaxf(accB[mt][ntl][i] + bias, 0.f));
                }
        }
        __syncthreads();

        // C: SIM += T_chunk @ Wa2_c^T (K=128 for this chunk)
        __builtin_amdgcn_s_setprio(1);
        #pragma unroll
        for (int ks = 0; ks < 4; ++ks) {
            int k0 = ks*32 + lg*8;
            bf16x8 aF[5];
            #pragma unroll
            for (int mt = 0; mt < 5; ++mt)
                aF[mt] = *(const bf16x8*)&smem[TL_OFF + SW256(mt*16 + c16, k0*2)];
            #pragma unroll
            for (int ntl = 0; ntl < 2; ++ntl) {
                int dd = w*32 + ntl*16 + c16;
                bf16x8 bF = *(const bf16x8*)&Wa2bf[(size_t)dd*AHH + c*128 + k0];
                #pragma unroll
                for (int mt = 0; mt < 5; ++mt)
                    accS[mt][ntl] = __builtin_amdgcn_mfma_f32_16x16x32_bf16(aF[mt], bF, accS[mt][ntl], 0, 0, 0);
            }
        }
        __builtin_amdgcn_s_setprio(0);
        __syncthreads();
    }

    // D: in-register softmax over kk + aggregate (no max-subtract: |sim| ~ 1e-3)
    float s_mtA[5], a_mtA[5], s_mtB[5], a_mtB[5];
    #pragma unroll
    for (int mt = 0; mt < 5; ++mt) {
        float sa = 0.f, aa = 0.f, sb = 0.f, ab = 0.f;
        #pragma unroll
        for (int i = 0; i < 4; ++i) {
            float eA = __expf(accS[mt][0][i] + ba2A);
            float eB = __expf(accS[mt][1][i] + ba2B);
            uint32_t pk = vpe_pk[mt][i];
            float vA = bf2f((ushort_t)(pk & 0xFFFFu));
            float vB = bf2f((ushort_t)(pk >> 16));
            sa += eA; aa += eA*vA;
            sb += eB; ab += eB*vB;
        }
        s_mtA[mt] = sa; a_mtA[mt] = aa; s_mtB[mt] = sb; a_mtB[mt] = ab;
    }
    bool eq0 = (lg==0), ge1 = (lg>=1), ge2 = (lg>=2), le1 = (lg<=1), le2 = (lg<=2), eq3 = (lg==3);
    float s0A = s_mtA[0] + (eq0 ? s_mtA[1] : 0.f);
    float s1A = (ge1 ? s_mtA[1] : 0.f) + (le1 ? s_mtA[2] : 0.f);
    float s2A = (ge2 ? s_mtA[2] : 0.f) + (le2 ? s_mtA[3] : 0.f);
    float s3A = (eq3 ? s_mtA[3] : 0.f) + s_mtA[4];
    float a0A = a_mtA[0] + (eq0 ? a_mtA[1] : 0.f);
    float a1A = (ge1 ? a_mtA[1] : 0.f) + (le1 ? a_mtA[2] : 0.f);
    float a2A = (ge2 ? a_mtA[2] : 0.f) + (le2 ? a_mtA[3] : 0.f);
    float a3A = (eq3 ? a_mtA[3] : 0.f) + a_mtA[4];
    float s0B = s_mtB[0] + (eq0 ? s_mtB[1] : 0.f);
    float s1B = (ge1 ? s_mtB[1] : 0.f) + (le1 ? s_mtB[2] : 0.f);
    float s2B = (ge2 ? s_mtB[2] : 0.f) + (le2 ? s_mtB[3] : 0.f);
    float s3B = (eq3 ? s_mtB[3] : 0.f) + s_mtB[4];
    float a0B = a_mtB[0] + (eq0 ? a_mtB[1] : 0.f);
    float a1B = (ge1 ? a_mtB[1] : 0.f) + (le1 ? a_mtB[2] : 0.f);
    float a2B = (ge2 ? a_mtB[2] : 0.f) + (le2 ? a_mtB[3] : 0.f);
    float a3B = (eq3 ? a_mtB[3] : 0.f) + a_mtB[4];

    #define RED2(v) { v += __shfl_xor(v, 16, 64); v += __shfl_xor(v, 32, 64); }
    RED2(s0A) RED2(s1A) RED2(s2A) RED2(s3A)
    RED2(a0A) RED2(a1A) RED2(a2A) RED2(a3A)
    RED2(s0B) RED2(s1B) RED2(s2B) RED2(s3B)
    RED2(a0B) RED2(a1B) RED2(a2B) RED2(a3B)
    #undef RED2

    float myS_A = (lg==0) ? s0A : (lg==1) ? s1A : (lg==2) ? s2A : s3A;
    float myA_A = (lg==0) ? a0A : (lg==1) ? a1A : (lg==2) ? a2A : a3A;
    float myS_B = (lg==0) ? s0B : (lg==1) ? s1B : (lg==2) ? s2B : s3B;
    float myA_B = (lg==0) ? a0B : (lg==1) ? a1B : (lg==2) ? a2B : a3B;
    float aggA = myA_A / myS_A;
    float aggB = myA_B / myS_B;

    // ---- epilogue: out = h + agg @ W3^T + b3 (reuse XL region as AGG[16][128]) ----
    // zero pad rows 4..15 (3072 B = 768 u32, 3 per thread)
    #pragma unroll
    for (int z = 0; z < 3; ++z)
        *(uint32_t*)&smem[XL_OFF + 1024 + (z*256 + tid)*4] = 0u;
    *(ushort_t*)&smem[XL_OFF + SW256(lg, dA*2)] = f2bf(aggA);
    *(ushort_t*)&smem[XL_OFF + SW256(lg, dB*2)] = f2bf(aggB);
    __syncthreads();

    f32x4 accO[2];
    accO[0] = (f32x4){0,0,0,0}; accO[1] = (f32x4){0,0,0,0};
    #pragma unroll
    for (int ks = 0; ks < 4; ++ks) {
        int k0 = ks*32 + lg*8;
        bf16x8 aF = *(const bf16x8*)&smem[XL_OFF + SW256(c16, k0*2)];
        #pragma unroll
        for (int ntl = 0; ntl < 2; ++ntl) {
            int n = (w*2 + ntl)*16 + c16;
            bf16x8 bF = *(const bf16x8*)&W3bf[(size_t)n*DD + k0];
            accO[ntl] = __builtin_amdgcn_mfma_f32_16x16x32_bf16(aF, bF, accO[ntl], 0, 0, 0);
        }
    }
    if (lg == 0) {
        #pragma unroll
        for (int ntl = 0; ntl < 2; ++ntl) {
            int n = (w*2 + ntl)*16 + c16;
            float bias = b3[n];
            #pragma unroll
            for (int i = 0; i < 4; ++i) {
                size_t o = (size_t)(p0+i)*DD + n;
                out[o] = accO[ntl][i] + bias + h[o];
            }
        }
    }
}

extern "C" void kernel_launch(void* const* d_in, const int* in_sizes, int n_in,
                              void* d_out, int out_size, void* d_ws, size_t ws_size,
                              hipStream_t stream) {
    const float* x    = (const float*)d_in[0];
    const float* pos  = (const float*)d_in[1];
    const float* W1   = (const float*)d_in[2];
    const float* b1   = (const float*)d_in[3];
    const float* W2   = (const float*)d_in[4];
    const float* b2   = (const float*)d_in[5];
    const float* W3   = (const float*)d_in[6];
    const float* b3   = (const float*)d_in[7];
    const float* Wqkv = (const float*)d_in[8];
    const float* Wp1  = (const float*)d_in[9];
    const float* bp1  = (const float*)d_in[10];
    const float* Wp2  = (const float*)d_in[11];
    const float* bp2  = (const float*)d_in[12];
    const float* Wa1  = (const float*)d_in[13];
    const float* ba1  = (const float*)d_in[14];
    const float* Wa2  = (const float*)d_in[15];
    const float* ba2  = (const float*)d_in[16];

    float* ws = (float*)d_ws;
    float* h   = ws;                                   // BN*DD f32
    ushort_t* qf = (ushort_t*)(ws + 2*(size_t)BN*DD);  // 3 x BN*DD bf16
    ushort_t* kf = qf + (size_t)BN*DD;
    ushort_t* vf = qf + 2*(size_t)BN*DD;
    int* idx = (int*)((char*)d_ws + 14680064);         // BN*KNB int
    ushort_t* wbf = (ushort_t*)((char*)d_ws + 15335424);
    ushort_t* Wa1bf = wbf;
    ushort_t* Wa2bf = wbf + 65536;
    ushort_t* W3bf  = wbf + 131072;

    k_mega<<<BN/4 + BN/32 + 72, 256, 0, stream>>>(x, pos, W1, b1, W2, b2, Wqkv,
                                                  Wa1, Wa2, W3, h, qf, kf, vf, idx, wbf);
    k_attn<<<BN/4, 256, 0, stream>>>(pos, qf, kf, vf, idx,
                                     Wp1, bp1, Wp2, bp2, Wa1bf, ba1, Wa2bf, ba2,
                                     W3bf, b3, h, (float*)d_out);
}

// Round 9
// 174.692 us; speedup vs baseline: 1.2677x; 1.2677x over previous
//
#include <hip/hip_runtime.h>
#include <stdint.h>

#define BB 2
#define NN 4096
#define KNB 20
#define DD 128
#define PHH 8
#define AHH 512
#define BN (BB*NN)

typedef unsigned short ushort_t;
typedef short bf16x8 __attribute__((ext_vector_type(8)));
typedef float f32x4 __attribute__((ext_vector_type(4)));

__device__ __forceinline__ uint32_t umin32(uint32_t a, uint32_t b) { return a < b ? a : b; }
__device__ __forceinline__ uint32_t umax32(uint32_t a, uint32_t b) { return a > b ? a : b; }

__device__ __forceinline__ ushort_t f2bf(float f) {   // RNE
    uint32_t x = __float_as_uint(f);
    return (ushort_t)((x + 0x7FFFu + ((x >> 16) & 1u)) >> 16);
}
__device__ __forceinline__ float bf2f(ushort_t u) {
    union { float f; uint32_t i; } c; c.i = ((uint32_t)u) << 16; return c.f;
}
__device__ __forceinline__ uint32_t cvt_pk_bf16(float lo, float hi) {
    uint32_t r;
    asm("v_cvt_pk_bf16_f32 %0, %1, %2" : "=v"(r) : "v"(lo), "v"(hi));
    return r;  // lo16 = bf16(lo), hi16 = bf16(hi)
}
__device__ __forceinline__ bf16x8 load_bfrag(const float* __restrict__ src) {
    float4 x = *(const float4*)src;
    float4 y = *(const float4*)(src + 4);
    union { bf16x8 v; uint32_t u[4]; } r;
    r.u[0] = cvt_pk_bf16(x.x, x.y);
    r.u[1] = cvt_pk_bf16(x.z, x.w);
    r.u[2] = cvt_pk_bf16(y.x, y.y);
    r.u[3] = cvt_pk_bf16(y.z, y.w);
    return r.v;
}

#define SW256(m, byteInRow) ((m)*256 + ((byteInRow) ^ (((m)&7) << 4)))
#define SW128(m, byteInRow) ((m)*128 + ((byteInRow) ^ (((m)&7) << 4)))

// ================= mega: knn(2048) || front(256) || prep(64) =================
__global__ __launch_bounds__(256) void k_mega(
        const float* __restrict__ x, const float* __restrict__ pos,
        const float* __restrict__ W1, const float* __restrict__ b1,
        const float* __restrict__ W2f, const float* __restrict__ b2,
        const float* __restrict__ Wqkvf,
        const float* __restrict__ Wa1, const float* __restrict__ Wa2,
        float* __restrict__ h, ushort_t* __restrict__ qf,
        ushort_t* __restrict__ kf, ushort_t* __restrict__ vf,
        int* __restrict__ idx, ushort_t* __restrict__ wbf) {
    __shared__ __align__(16) char smem[16896];
    int tid = threadIdx.x, w = tid >> 6, lane = tid & 63;
    int bid = blockIdx.x;

    if (bid < BN/4) {
        // ---------------- KNN: one wave per query ----------------
        int p = bid*4 + w;
        int b = p >> 12;
        float qx = pos[p*3+0], qy = pos[p*3+1], qz = pos[p*3+2];
        const float* pb = pos + (size_t)b*NN*3;
        uint32_t bk[KNB];
        #pragma unroll
        for (int i = 0; i < KNB; ++i) bk[i] = 0xFFFFFFFFu;
        for (int i = 0; i < NN/64; ++i) {
            int j = i*64 + lane;
            float dx = qx - pb[j*3+0];
            float dy = qy - pb[j*3+1];
            float dz = qz - pb[j*3+2];
            float d2 = dx*dx + dy*dy + dz*dz;
            uint32_t key = (__float_as_uint(d2) & 0xFFFFF000u) | (uint32_t)j;
            if (key < bk[KNB-1]) {
                uint32_t c = key;
                #pragma unroll
                for (int t = 0; t < KNB; ++t) {
                    uint32_t lo = umin32(c, bk[t]);
                    uint32_t hi = umax32(c, bk[t]);
                    bk[t] = lo; c = hi;
                }
            }
        }
        for (int r = 0; r < KNB; ++r) {
            uint32_t m = bk[0];
            #pragma unroll
            for (int s = 1; s < 64; s <<= 1)
                m = umin32(m, (uint32_t)__shfl_xor((int)m, s, 64));
            if (lane == 0) idx[(size_t)p*KNB + r] = (int)(m & 0xFFFu);
            bool win = (bk[0] == m);
            #pragma unroll
            for (int t = 0; t < KNB-1; ++t) bk[t] = win ? bk[t+1] : bk[t];
            bk[KNB-1] = win ? 0xFFFFFFFFu : bk[KNB-1];
        }
    } else if (bid < BN/4 + BN/32) {
        // ---------------- front: lin1 + lin2 + qkv (MFMA) ----------------
        float* xs = (float*)(smem + 16384);
        int p0 = (bid - BN/4) * 32;
        if (tid < 96) xs[tid] = x[(size_t)p0*3 + tid];
        __syncthreads();

        #pragma unroll
        for (int it = 0; it < 16; ++it) {
            int lin = it*256 + tid;
            int m = lin >> 7, d = lin & 127;
            float hv = b1[d] + xs[m*3+0]*W1[d*3+0] + xs[m*3+1]*W1[d*3+1] + xs[m*3+2]*W1[d*3+2];
            h[(size_t)(p0+m)*DD + d] = hv;
            *(ushort_t*)&smem[SW256(m, d*2)] = f2bf(hv);
        }
        __syncthreads();

        {   // h1 = h@W2^T + b2 -> LDS @8192
            f32x4 acc[2][2];
            #pragma unroll
            for (int mt = 0; mt < 2; ++mt)
                #pragma unroll
                for (int ntl = 0; ntl < 2; ++ntl) acc[mt][ntl] = (f32x4){0,0,0,0};
            #pragma unroll
            for (int ks = 0; ks < 4; ++ks) {
                int k0 = ks*32 + (lane >> 4)*8;
                bf16x8 aF[2];
                #pragma unroll
                for (int mt = 0; mt < 2; ++mt)
                    aF[mt] = *(const bf16x8*)&smem[SW256(mt*16 + (lane & 15), k0*2)];
                #pragma unroll
                for (int ntl = 0; ntl < 2; ++ntl) {
                    int n = (2*w + ntl)*16 + (lane & 15);
                    bf16x8 bF = load_bfrag(W2f + (size_t)n*DD + k0);
                    #pragma unroll
                    for (int mt = 0; mt < 2; ++mt)
                        acc[mt][ntl] = __builtin_amdgcn_mfma_f32_16x16x32_bf16(aF[mt], bF, acc[mt][ntl], 0, 0, 0);
                }
            }
            #pragma unroll
            for (int ntl = 0; ntl < 2; ++ntl) {
                int n = (2*w + ntl)*16 + (lane & 15);
                float bias = b2[n];
                #pragma unroll
                for (int mt = 0; mt < 2; ++mt)
                    #pragma unroll
                    for (int i = 0; i < 4; ++i) {
                        int m = mt*16 + (lane >> 4)*4 + i;
                        *(ushort_t*)&smem[8192 + SW256(m, n*2)] = f2bf(acc[mt][ntl][i] + bias);
                    }
            }
        }
        __syncthreads();

        {   // qkv = h1@Wqkv^T, bf16 out
            f32x4 acc[2][6];
            #pragma unroll
            for (int mt = 0; mt < 2; ++mt)
                #pragma unroll
                for (int ntl = 0; ntl < 6; ++ntl) acc[mt][ntl] = (f32x4){0,0,0,0};
            #pragma unroll
            for (int ks = 0; ks < 4; ++ks) {
                int k0 = ks*32 + (lane >> 4)*8;
                bf16x8 aF[2];
                #pragma unroll
                for (int mt = 0; mt < 2; ++mt)
                    aF[mt] = *(const bf16x8*)&smem[8192 + SW256(mt*16 + (lane & 15), k0*2)];
                #pragma unroll
                for (int ntl = 0; ntl < 6; ++ntl) {
                    int n = (w*6 + ntl)*16 + (lane & 15);
                    bf16x8 bF = load_bfrag(Wqkvf + (size_t)n*DD + k0);
                    #pragma unroll
                    for (int mt = 0; mt < 2; ++mt)
                        acc[mt][ntl] = __builtin_amdgcn_mfma_f32_16x16x32_bf16(aF[mt], bF, acc[mt][ntl], 0, 0, 0);
                }
            }
            #pragma unroll
            for (int ntl = 0; ntl < 6; ++ntl) {
                int n = (w*6 + ntl)*16 + (lane & 15);
                int r = n >> 7, d = n & 127;
                ushort_t* dst = (r == 0) ? qf : (r == 1) ? kf : vf;
                #pragma unroll
                for (int mt = 0; mt < 2; ++mt)
                    #pragma unroll
                    for (int i = 0; i < 4; ++i) {
                        int m = mt*16 + (lane >> 4)*4 + i;
                        dst[(size_t)(p0+m)*DD + d] = f2bf(acc[mt][ntl][i]);
                    }
            }
        }
    } else {
        // ---------------- prep: Wa1|Wa2 f32 -> bf16 ----------------
        int base = (bid - (BN/4 + BN/32)) * 2048 + tid * 8;
        const float* src = (base < 65536) ? (Wa1 + base) : (Wa2 + (base - 65536));
        union { ushort_t u[8]; uint4 q; } pk;
        #pragma unroll
        for (int i = 0; i < 8; ++i) pk.u[i] = f2bf(src[i]);
        *(uint4*)&wbf[base] = pk.q;
    }
}

// ======== attn: pe-MFMA + attn-MLP MFMA + in-register softmax/aggregate ========
// XCD-batch swizzle: XCDs 0-3 -> batch 0, XCDs 4-7 -> batch 1 (k/v working set
// per XCD-L2 halves to 2 MB -> gather rows stay L2-resident).
// LDS: XL bf16[80][128]swz @0 (20480) | TL bf16[80][64]swz @20480 (10240)
//      PH bf16[80][8] @30720 (1280) | NIDX @32000 (320). Total 32320 -> 4-5 blk/CU.
#define XL_OFF 0
#define TL_OFF 20480
#define PH_OFF 30720
#define NIDX_OFF 32000

__global__ __launch_bounds__(256, 4) void k_attn(
        const float* __restrict__ pos,
        const ushort_t* __restrict__ qf, const ushort_t* __restrict__ kf,
        const ushort_t* __restrict__ vf, const int* __restrict__ idx,
        const float* __restrict__ Wp1, const float* __restrict__ bp1,
        const float* __restrict__ Wp2, const float* __restrict__ bp2,
        const ushort_t* __restrict__ Wa1bf, const float* __restrict__ ba1,
        const ushort_t* __restrict__ Wa2bf, const float* __restrict__ ba2,
        float* __restrict__ agg) {
    __shared__ __align__(16) char smem[32320];
    int* nidx = (int*)(smem + NIDX_OFF);

    int tid = threadIdx.x, w = tid >> 6, lane = tid & 63;
    int lg = lane >> 4, c16 = lane & 15;
    // XCD-batch swizzle (blocks dispatch round-robin over 8 XCDs; 2048 % 8 == 0)
    int bid = blockIdx.x;
    int xcd = bid & 7, sloc = bid >> 3;
    int b = xcd >> 2;
    int p0 = b*NN + ((xcd & 3)*256 + sloc)*4;

    if (tid < 80) nidx[tid] = idx[(size_t)(p0 + tid/20)*KNB + (tid%20)];
    __syncthreads();

    // A1: pos-MLP hidden, one thread per m-row, packed bf16[8]
    if (tid < 80) {
        int m = tid, g = m / 20;
        int j = nidx[m];
        const float* pq = pos + (size_t)(p0+g)*3;
        const float* pn = pos + (size_t)(b*NN+j)*3;
        float r0 = pq[0]-pn[0], r1 = pq[1]-pn[1], r2 = pq[2]-pn[2];
        union { ushort_t u[8]; uint4 q; } pk;
        #pragma unroll
        for (int jj = 0; jj < PHH; ++jj) {
            float a = bp1[jj] + r0*Wp1[jj*3+0] + r1*Wp1[jj*3+1] + r2*Wp1[jj*3+2];
            pk.u[jj] = f2bf(fmaxf(a, 0.f));
        }
        *(uint4*)&smem[PH_OFF + m*16] = pk.q;
    }
    __syncthreads();

    int dA = w*32 + c16, dB = w*32 + 16 + c16;     // this lane's two d-columns
    float bp2A = bp2[dA], bp2B = bp2[dB];
    float ba2A = ba2[dA], ba2B = ba2[dB];

    // pe-MFMA B-fragments (K padded 8->32: only lg==0 lanes carry data)
    bf16x8 bP0 = {0,0,0,0,0,0,0,0}, bP1 = {0,0,0,0,0,0,0,0};
    if (lg == 0) {
        bP0 = load_bfrag(Wp2 + (size_t)dA*PHH);
        bP1 = load_bfrag(Wp2 + (size_t)dB*PHH);
    }

    float qv[4][2];
    #pragma unroll
    for (int g = 0; g < 4; ++g) {
        qv[g][0] = bf2f(qf[(size_t)(p0+g)*DD + dA]);
        qv[g][1] = bf2f(qf[(size_t)(p0+g)*DD + dB]);
    }

    uint32_t vpe_pk[5][4];   // (v+pe) packed bf16 pairs (dA,dB), [mt][i]

    // A2 fused with pe-MFMA, per m-tile
    #pragma unroll
    for (int mt = 0; mt < 5; ++mt) {
        bf16x8 aP = {0,0,0,0,0,0,0,0};
        if (lg == 0) aP = *(const bf16x8*)&smem[PH_OFF + (mt*16 + c16)*16];
        f32x4 accP0 = (f32x4){0,0,0,0}, accP1 = (f32x4){0,0,0,0};
        accP0 = __builtin_amdgcn_mfma_f32_16x16x32_bf16(aP, bP0, accP0, 0, 0, 0);
        accP1 = __builtin_amdgcn_mfma_f32_16x16x32_bf16(aP, bP1, accP1, 0, 0, 0);
        // q select: g(mt,lg) = [0, lg>=1, 1+(lg>=2), 2+(lg==3), 3]
        float qsA = (mt==0) ? qv[0][0]
                  : (mt==1) ? (lg>=1 ? qv[1][0] : qv[0][0])
                  : (mt==2) ? (lg>=2 ? qv[2][0] : qv[1][0])
                  : (mt==3) ? (lg==3 ? qv[3][0] : qv[2][0])
                  : qv[3][0];
        float qsB = (mt==0) ? qv[0][1]
                  : (mt==1) ? (lg>=1 ? qv[1][1] : qv[0][1])
                  : (mt==2) ? (lg>=2 ? qv[2][1] : qv[1][1])
                  : (mt==3) ? (lg==3 ? qv[3][1] : qv[2][1])
                  : qv[3][1];
        #pragma unroll
        for (int i = 0; i < 4; ++i) {
            int m = mt*16 + lg*4 + i;
            int j = nidx[m];
            const ushort_t* kr = kf + (size_t)(b*NN+j)*DD;
            const ushort_t* vr = vf + (size_t)(b*NN+j)*DD;
            float peA = accP0[i] + bp2A;
            float peB = accP1[i] + bp2B;
            *(ushort_t*)&smem[XL_OFF + SW256(m, dA*2)] = f2bf(qsA - bf2f(kr[dA]) + peA);
            *(ushort_t*)&smem[XL_OFF + SW256(m, dB*2)] = f2bf(qsB - bf2f(kr[dB]) + peB);
            vpe_pk[mt][i] = cvt_pk_bf16(bf2f(vr[dA]) + peA, bf2f(vr[dB]) + peB);
        }
    }
    __syncthreads();

    // attn-MLP: hidden in 8 chunks of 64; SIM accumulates in registers
    f32x4 accS[5][2];
    #pragma unroll
    for (int mt = 0; mt < 5; ++mt)
        #pragma unroll
        for (int ntl = 0; ntl < 2; ++ntl) accS[mt][ntl] = (f32x4){0,0,0,0};

    for (int c = 0; c < 8; ++c) {
        f32x4 accB[5];
        #pragma unroll
        for (int mt = 0; mt < 5; ++mt) accB[mt] = (f32x4){0,0,0,0};
        #pragma unroll
        for (int ks = 0; ks < 4; ++ks) {
            int k0 = ks*32 + lg*8;
            bf16x8 aF[5];
            #pragma unroll
            for (int mt = 0; mt < 5; ++mt)
                aF[mt] = *(const bf16x8*)&smem[XL_OFF + SW256(mt*16 + c16, k0*2)];
            bf16x8 bF = *(const bf16x8*)&Wa1bf[(size_t)(c*64 + w*16 + c16)*DD + k0];
            #pragma unroll
            for (int mt = 0; mt < 5; ++mt)
                accB[mt] = __builtin_amdgcn_mfma_f32_16x16x32_bf16(aF[mt], bF, accB[mt], 0, 0, 0);
        }
        {
            int al = w*16 + c16;
            float bias = ba1[c*64 + al];
            #pragma unroll
            for (int mt = 0; mt < 5; ++mt)
                #pragma unroll
                for (int i = 0; i < 4; ++i) {
                    int m = mt*16 + lg*4 + i;
                    *(ushort_t*)&smem[TL_OFF + SW128(m, al*2)] = f2bf(fmaxf(accB[mt][i] + bias, 0.f));
                }
        }
        __syncthreads();

        #pragma unroll
        for (int ks = 0; ks < 2; ++ks) {
            int k0 = ks*32 + lg*8;
            bf16x8 aF[5];
            #pragma unroll
            for (int mt = 0; mt < 5; ++mt)
                aF[mt] = *(const bf16x8*)&smem[TL_OFF + SW128(mt*16 + c16, k0*2)];
            #pragma unroll
            for (int ntl = 0; ntl < 2; ++ntl) {
                int dd = w*32 + ntl*16 + c16;
                bf16x8 bF = *(const bf16x8*)&Wa2bf[(size_t)dd*AHH + c*64 + k0];
                #pragma unroll
                for (int mt = 0; mt < 5; ++mt)
                    accS[mt][ntl] = __builtin_amdgcn_mfma_f32_16x16x32_bf16(aF[mt], bF, accS[mt][ntl], 0, 0, 0);
            }
        }
        __syncthreads();
    }

    // D: in-register softmax over kk + aggregate (no max-subtract: |sim| ~ 1e-3)
    float s_mtA[5], a_mtA[5], s_mtB[5], a_mtB[5];
    #pragma unroll
    for (int mt = 0; mt < 5; ++mt) {
        float sa = 0.f, aa = 0.f, sb = 0.f, ab = 0.f;
        #pragma unroll
        for (int i = 0; i < 4; ++i) {
            float eA = __expf(accS[mt][0][i] + ba2A);
            float eB = __expf(accS[mt][1][i] + ba2B);
            uint32_t pk = vpe_pk[mt][i];
            float vA = bf2f((ushort_t)(pk & 0xFFFFu));
            float vB = bf2f((ushort_t)(pk >> 16));
            sa += eA; aa += eA*vA;
            sb += eB; ab += eB*vB;
        }
        s_mtA[mt] = sa; a_mtA[mt] = aa; s_mtB[mt] = sb; a_mtB[mt] = ab;
    }
    bool eq0 = (lg==0), ge1 = (lg>=1), ge2 = (lg>=2), le1 = (lg<=1), le2 = (lg<=2), eq3 = (lg==3);
    float s0A = s_mtA[0] + (eq0 ? s_mtA[1] : 0.f);
    float s1A = (ge1 ? s_mtA[1] : 0.f) + (le1 ? s_mtA[2] : 0.f);
    float s2A = (ge2 ? s_mtA[2] : 0.f) + (le2 ? s_mtA[3] : 0.f);
    float s3A = (eq3 ? s_mtA[3] : 0.f) + s_mtA[4];
    float a0A = a_mtA[0] + (eq0 ? a_mtA[1] : 0.f);
    float a1A = (ge1 ? a_mtA[1] : 0.f) + (le1 ? a_mtA[2] : 0.f);
    float a2A = (ge2 ? a_mtA[2] : 0.f) + (le2 ? a_mtA[3] : 0.f);
    float a3A = (eq3 ? a_mtA[3] : 0.f) + a_mtA[4];
    float s0B = s_mtB[0] + (eq0 ? s_mtB[1] : 0.f);
    float s1B = (ge1 ? s_mtB[1] : 0.f) + (le1 ? s_mtB[2] : 0.f);
    float s2B = (ge2 ? s_mtB[2] : 0.f) + (le2 ? s_mtB[3] : 0.f);
    float s3B = (eq3 ? s_mtB[3] : 0.f) + s_mtB[4];
    float a0B = a_mtB[0] + (eq0 ? a_mtB[1] : 0.f);
    float a1B = (ge1 ? a_mtB[1] : 0.f) + (le1 ? a_mtB[2] : 0.f);
    float a2B = (ge2 ? a_mtB[2] : 0.f) + (le2 ? a_mtB[3] : 0.f);
    float a3B = (eq3 ? a_mtB[3] : 0.f) + a_mtB[4];

    #define RED2(v) { v += __shfl_xor(v, 16, 64); v += __shfl_xor(v, 32, 64); }
    RED2(s0A) RED2(s1A) RED2(s2A) RED2(s3A)
    RED2(a0A) RED2(a1A) RED2(a2A) RED2(a3A)
    RED2(s0B) RED2(s1B) RED2(s2B) RED2(s3B)
    RED2(a0B) RED2(a1B) RED2(a2B) RED2(a3B)
    #undef RED2

    float myS_A = (lg==0) ? s0A : (lg==1) ? s1A : (lg==2) ? s2A : s3A;
    float myA_A = (lg==0) ? a0A : (lg==1) ? a1A : (lg==2) ? a2A : a3A;
    float myS_B = (lg==0) ? s0B : (lg==1) ? s1B : (lg==2) ? s2B : s3B;
    float myA_B = (lg==0) ? a0B : (lg==1) ? a1B : (lg==2) ? a2B : a3B;
    agg[(size_t)(p0+lg)*DD + dA] = myA_A / myS_A;
    agg[(size_t)(p0+lg)*DD + dB] = myA_B / myS_B;
}

// ---------------- out = h + agg @ W3.T + b3 (MFMA) ----------------
__global__ __launch_bounds__(256) void k_out(
        const float* __restrict__ agg, const float* __restrict__ h,
        const float* __restrict__ W3f, const float* __restrict__ b3,
        float* __restrict__ out) {
    __shared__ __align__(16) char smem[8192];
    int tid = threadIdx.x, w = tid >> 6, lane = tid & 63;
    int p0 = blockIdx.x * 32;

    #pragma unroll
    for (int it = 0; it < 16; ++it) {
        int lin = it*256 + tid;
        int m = lin >> 7, d = lin & 127;
        *(ushort_t*)&smem[SW256(m, d*2)] = f2bf(agg[(size_t)(p0+m)*DD + d]);
    }
    __syncthreads();

    f32x4 acc[2][2];
    #pragma unroll
    for (int mt = 0; mt < 2; ++mt)
        #pragma unroll
        for (int ntl = 0; ntl < 2; ++ntl) acc[mt][ntl] = (f32x4){0,0,0,0};
    #pragma unroll
    for (int ks = 0; ks < 4; ++ks) {
        int k0 = ks*32 + (lane >> 4)*8;
        bf16x8 aF[2];
        #pragma unroll
        for (int mt = 0; mt < 2; ++mt)
            aF[mt] = *(const bf16x8*)&smem[SW256(mt*16 + (lane & 15), k0*2)];
        #pragma unroll
        for (int ntl = 0; ntl < 2; ++ntl) {
            int n = (2*w + ntl)*16 + (lane & 15);
            bf16x8 bF = load_bfrag(W3f + (size_t)n*DD + k0);
            #pragma unroll
            for (int mt = 0; mt < 2; ++mt)
                acc[mt][ntl] = __builtin_amdgcn_mfma_f32_16x16x32_bf16(aF[mt], bF, acc[mt][ntl], 0, 0, 0);
        }
    }
    #pragma unroll
    for (int ntl = 0; ntl < 2; ++ntl) {
        int n = (2*w + ntl)*16 + (lane & 15);
        float bias = b3[n];
        #pragma unroll
        for (int mt = 0; mt < 2; ++mt)
            #pragma unroll
            for (int i = 0; i < 4; ++i) {
                int m = mt*16 + (lane >> 4)*4 + i;
                size_t o = (size_t)(p0+m)*DD + n;
                out[o] = acc[mt][ntl][i] + bias + h[o];
            }
    }
}

extern "C" void kernel_launch(void* const* d_in, const int* in_sizes, int n_in,
                              void* d_out, int out_size, void* d_ws, size_t ws_size,
                              hipStream_t stream) {
    const float* x    = (const float*)d_in[0];
    const float* pos  = (const float*)d_in[1];
    const float* W1   = (const float*)d_in[2];
    const float* b1   = (const float*)d_in[3];
    const float* W2   = (const float*)d_in[4];
    const float* b2   = (const float*)d_in[5];
    const float* W3   = (const float*)d_in[6];
    const float* b3   = (const float*)d_in[7];
    const float* Wqkv = (const float*)d_in[8];
    const float* Wp1  = (const float*)d_in[9];
    const float* bp1  = (const float*)d_in[10];
    const float* Wp2  = (const float*)d_in[11];
    const float* bp2  = (const float*)d_in[12];
    const float* Wa1  = (const float*)d_in[13];
    const float* ba1  = (const float*)d_in[14];
    const float* Wa2  = (const float*)d_in[15];
    const float* ba2  = (const float*)d_in[16];

    float* ws = (float*)d_ws;
    float* h   = ws;                                   // BN*DD f32
    float* agg = ws + (size_t)BN*DD;                   // BN*DD f32
    ushort_t* qf = (ushort_t*)(ws + 2*(size_t)BN*DD);  // 3 x BN*DD bf16
    ushort_t* kf = qf + (size_t)BN*DD;
    ushort_t* vf = qf + 2*(size_t)BN*DD;
    int* idx = (int*)((char*)d_ws + 14680064);         // BN*KNB int
    ushort_t* wbf = (ushort_t*)((char*)d_ws + 15335424);
    ushort_t* Wa1bf = wbf;
    ushort_t* Wa2bf = wbf + 65536;

    k_mega<<<BN/4 + BN/32 + 64, 256, 0, stream>>>(x, pos, W1, b1, W2, b2, Wqkv,
                                                  Wa1, Wa2, h, qf, kf, vf, idx, wbf);
    k_attn<<<BN/4, 256, 0, stream>>>(pos, qf, kf, vf, idx,
                                     Wp1, bp1, Wp2, bp2, Wa1bf, ba1, Wa2bf, ba2, agg);
    k_out <<<BN/32, 256, 0, stream>>>(agg, h, W3, b3, (float*)d_out);
}